// Round 5
// baseline (166.787 us; speedup 1.0000x reference)
//
#include <hip/hip_runtime.h>
#include <hip/hip_bf16.h>

#define NBS 8
#define NT 32
#define NF 128
#define NDIN 64
#define NNH 8
#define NDOUT 64

typedef __bf16 bf16_t;
typedef __bf16 bf16x8 __attribute__((ext_vector_type(8)));
typedef float f32x4 __attribute__((ext_vector_type(4)));

// ---------------- kernel 1: q/k projection ----------------
// One wave per (t,f): q[b,he] = sum_d X[b,f,t,d] * Wq[t,f,d,he], all 8 b at once.
// Wq/Wk/X each read exactly once from HBM -> ~54MB -> memory-bound ~9us.
__global__ __launch_bounds__(256, 4)
void qk_project_kernel(const float* __restrict__ X,
                       const float* __restrict__ Wq,
                       const float* __restrict__ Wk,
                       float* __restrict__ q_ws,
                       float* __restrict__ k_ws)
{
    __shared__ float lx[4][8][64];
    const int w = threadIdx.x >> 6, lane = threadIdx.x & 63;
    const int gw = blockIdx.x * 4 + w;
    const int t = gw >> 7, f = gw & 127;

    {
        const int b = lane >> 3, d8 = (lane & 7) << 3;
        const float* src = &X[(((size_t)b * NF + f) * NT + t) * NDIN + d8];
        const float4 v0 = *(const float4*)src;
        const float4 v1 = *(const float4*)(src + 4);
        *(float4*)&lx[w][b][d8]     = v0;
        *(float4*)&lx[w][b][d8 + 4] = v1;
    }
    __syncthreads();

    const int dq = lane >> 4, he = lane & 15;
    const float* wq = Wq + ((size_t)t * NF + f) * (NDIN * 16);
    const float* wk = Wk + ((size_t)t * NF + f) * (NDIN * 16);
    float qa[8] = {0,0,0,0,0,0,0,0}, ka[8] = {0,0,0,0,0,0,0,0};
    for (int d0 = 0; d0 < NDIN; d0 += 4) {
        const int d = d0 + dq;
        const float wqv = wq[d * 16 + he];
        const float wkv = wk[d * 16 + he];
#pragma unroll
        for (int b = 0; b < 8; ++b) {
            const float x = lx[w][b][d];
            qa[b] = fmaf(x, wqv, qa[b]);
            ka[b] = fmaf(x, wkv, ka[b]);
        }
    }
#pragma unroll
    for (int b = 0; b < 8; ++b) {
        qa[b] += __shfl_xor(qa[b], 16); qa[b] += __shfl_xor(qa[b], 32);
        ka[b] += __shfl_xor(ka[b], 16); ka[b] += __shfl_xor(ka[b], 32);
    }
#pragma unroll
    for (int bb = 0; bb < 2; ++bb) {
        const int b = dq + bb * 4;
        q_ws[(((size_t)b * NT + t) * 16 + he) * NF + f] = qa[b];
        k_ws[(((size_t)b * NT + t) * 16 + he) * NF + f] = ka[b];
    }
}

// ---------------- kernel 2: attention + output GEMMs (barrier-free tasks) ----------------
// One block per (b,t). 1024 threads = 16 waves. Wave w: row-tile rt=w&7,
// heads h = 4*(w>>3)+task. Softmax in MFMA A-frag layout, P in registers,
// V through per-wave private LDS scratch, 3 barriers total.
// waves_per_eu(4,4): LDS caps us at 1 block/CU (= 4 waves/EU) anyway; pinning
// max=4 stops the allocator from squeezing into the 64-VGPR/8-wave bucket
// (round-4 regression: 64 VGPRs -> 264MB scratch-spill traffic).
__global__ __attribute__((amdgpu_flat_work_group_size(1024, 1024)))
           __attribute__((amdgpu_waves_per_eu(4, 4)))
void spatial_attn_kernel(const float* __restrict__ X,
                         const float* __restrict__ q_ws,
                         const float* __restrict__ k_ws,
                         const float* __restrict__ Wkey,
                         const float* __restrict__ U,
                         const float* __restrict__ AC,
                         const float* __restrict__ Alpha,
                         const float* __restrict__ Wo,
                         const float* __restrict__ Bias,
                         float* __restrict__ Out)
{
    const int blk  = blockIdx.x;
    const int b    = blk & 7;
    const int t    = blk >> 3;
    const int tid  = threadIdx.x;
    const int w    = tid >> 6;
    const int lane = tid & 63;
    const int cq   = lane & 15;
    const int rq   = lane >> 4;
    const int rt   = w & 7;        // row tile
    const int hb   = w >> 3;       // head group: h = 4*hb + task
    const int frow = 16 * rt + cq;

    // LDS carve: 159744 B total (<= 160 KiB)
    __shared__ __align__(16) unsigned char smem[159744];
    bf16_t (*XT)[NF + 8]        = (bf16_t (*)[NF + 8])(smem);             // [64][136]    17408
    float4 (*kv)[136]           = (float4 (*)[136])(smem + 17408);        // [8][136]     17408  {k0,k1,u0,u1}(h,l)
    float4 (*qf)[128]           = (float4 (*)[128])(smem + 34816);        // [8][128]     16384  {q0,q1,kf0,kf1}(h,f)
    bf16_t (*WTall)[NDOUT][72]  = (bf16_t (*)[NDOUT][72])(smem + 51200);  // [8][64][72]  73728
    bf16_t (*Vscr)[16][68]      = (bf16_t (*)[16][68])(smem + 124928);    // [16][16][68] 34816
    float  (*Red)[16][68]       = (float  (*)[16][68])(smem + 124928);    // overlay f32 [8][16][68]

    // ---- stage XT (X^T bf16) ----
#pragma unroll
    for (int r = 0; r < 2; ++r) {
        const int idx = tid + r * 1024;
        const int f = idx >> 4, d4 = (idx & 15) << 2;
        const float4 v = *(const float4*)&X[(((size_t)b * NF + f) * NT + t) * NDIN + d4];
        XT[d4 + 0][f] = (bf16_t)v.x; XT[d4 + 1][f] = (bf16_t)v.y;
        XT[d4 + 2][f] = (bf16_t)v.z; XT[d4 + 3][f] = (bf16_t)v.w;
    }
    // ---- stage kv and qf: one thread per (h,l) ----
    {
        const int hh = tid >> 7, l = tid & 127;
        const size_t qkb = ((size_t)b * NT + t) * 16;
        const float k0 = k_ws[(qkb + 2 * hh + 0) * NF + l];
        const float k1 = k_ws[(qkb + 2 * hh + 1) * NF + l];
        const float2 u01 = *(const float2*)&U[((size_t)t * NF + l) * 2];
        kv[hh][17 * (l >> 4) + (l & 15)] = make_float4(k0, k1, u01.x, u01.y);
        const float q0 = q_ws[(qkb + 2 * hh + 0) * NF + l];
        const float q1 = q_ws[(qkb + 2 * hh + 1) * NF + l];
        qf[hh][l] = make_float4(q0, q1, k0, k1);
    }
    // ---- stage WTall[h][o][d] = W[t][h*64+d][o] (bf16) ----
#pragma unroll
    for (int rep = 0; rep < 8; ++rep) {
        const int flat = rep * 1024 + tid;
        const int h = flat >> 10, f10 = flat & 1023;
        const int d = f10 >> 4, o4 = (f10 & 15) << 2;
        const float4 v = *(const float4*)&Wo[((size_t)t * 512 + h * 64 + d) * NDOUT + o4];
        WTall[h][o4 + 0][d] = (bf16_t)v.x; WTall[h][o4 + 1][d] = (bf16_t)v.y;
        WTall[h][o4 + 2][d] = (bf16_t)v.z; WTall[h][o4 + 3][d] = (bf16_t)v.w;
    }

    const float alpha_t = Alpha[t];
    const float wk00 = Wkey[t * 4 + 0], wk01 = Wkey[t * 4 + 1];
    const float wk10 = Wkey[t * 4 + 2], wk11 = Wkey[t * 4 + 3];

    __syncthreads();   // barrier 1: staging complete

    f32x4 oacc[4] = { {0.f,0.f,0.f,0.f}, {0.f,0.f,0.f,0.f}, {0.f,0.f,0.f,0.f}, {0.f,0.f,0.f,0.f} };

#pragma unroll 1
    for (int task = 0; task < 4; ++task) {
        const int h = 4 * hb + task;
        const float4 qq = qf[h][frow];            // {q0,q1,kf0,kf1} for this row
        const float q0 = qq.x, q1 = qq.y, kf0 = qq.z, kf1 = qq.w;
        const float v1 = 2.f * alpha_t * AC[t * NNH + h];
        const float c0 = (q0 - alpha_t) * wk00 + (q1 + v1) * wk10;
        const float c1 = (q0 - alpha_t) * wk01 + (q1 + v1) * wk11;

        // scores in A-frag layout: sc[kt][j] = S[frow][kt*32 + rq*8 + j]
        float sc[4][8];
        float rowmax = -3.0e38f;
#pragma unroll
        for (int kt = 0; kt < 4; ++kt) {
            const int s  = kt * 2 + (rq >> 1);
            const int i0 = (rq & 1) << 3;
            const float4* kvp = &kv[h][17 * s + i0];
            float del = (float)(kt * 32 + rq * 8 - frow);
#pragma unroll
            for (int j = 0; j < 8; ++j) {
                const float4 kj = kvp[j];
                const float sv = q0 * kj.x + q1 * kj.y + kf0 * kj.z + kf1 * kj.w
                               + (c0 * del + c1) * del;
                sc[kt][j] = sv;
                rowmax = fmaxf(rowmax, sv);
                del += 1.f;
            }
        }
        rowmax = fmaxf(rowmax, __shfl_xor(rowmax, 16));
        rowmax = fmaxf(rowmax, __shfl_xor(rowmax, 32));
        float sum = 0.f;
#pragma unroll
        for (int kt = 0; kt < 4; ++kt)
#pragma unroll
            for (int j = 0; j < 8; ++j) {
                sc[kt][j] = __expf(sc[kt][j] - rowmax);
                sum += sc[kt][j];
            }
        sum += __shfl_xor(sum, 16);
        sum += __shfl_xor(sum, 32);
        const float rinv = 1.f / sum;

        // GEMM1: V[16x64] = P[16x128] @ X[128x64]
        f32x4 vacc[4] = { {0.f,0.f,0.f,0.f}, {0.f,0.f,0.f,0.f}, {0.f,0.f,0.f,0.f}, {0.f,0.f,0.f,0.f} };
#pragma unroll
        for (int kt = 0; kt < 4; ++kt) {
            bf16x8 pf;
#pragma unroll
            for (int j = 0; j < 8; ++j) pf[j] = (bf16_t)(sc[kt][j] * rinv);
#pragma unroll
            for (int ct = 0; ct < 4; ++ct) {
                const bf16x8 bb = *(const bf16x8*)&XT[ct * 16 + cq][kt * 32 + rq * 8];
                vacc[ct] = __builtin_amdgcn_mfma_f32_16x16x32_bf16(pf, bb, vacc[ct], 0, 0, 0);
            }
        }
        // V C-frags -> private wave scratch (intra-wave dep only, no barrier)
#pragma unroll
        for (int ct = 0; ct < 4; ++ct)
#pragma unroll
            for (int rr = 0; rr < 4; ++rr)
                Vscr[w][rq * 4 + rr][ct * 16 + cq] = (bf16_t)vacc[ct][rr];

        // GEMM2: oacc += V[16x64] @ W_h[64x64]
#pragma unroll
        for (int kt = 0; kt < 2; ++kt) {
            const bf16x8 a = *(const bf16x8*)&Vscr[w][cq][kt * 32 + rq * 8];
#pragma unroll
            for (int ct = 0; ct < 4; ++ct) {
                const bf16x8 bw = *(const bf16x8*)&WTall[h][ct * 16 + cq][kt * 32 + rq * 8];
                oacc[ct] = __builtin_amdgcn_mfma_f32_16x16x32_bf16(a, bw, oacc[ct], 0, 0, 0);
            }
        }
    }

    __syncthreads();   // barrier 2: all tasks done (Vscr free for Red overlay)

    if (w >= 8) {
#pragma unroll
        for (int ct = 0; ct < 4; ++ct)
#pragma unroll
            for (int rr = 0; rr < 4; ++rr)
                Red[w - 8][rq * 4 + rr][ct * 16 + cq] = oacc[ct][rr];
    }
    __syncthreads();   // barrier 3: partials visible

    if (w < 8) {
#pragma unroll
        for (int ct = 0; ct < 4; ++ct) {
#pragma unroll
            for (int rr = 0; rr < 4; ++rr) {
                const int f = 16 * rt + rq * 4 + rr;
                const int o = ct * 16 + cq;
                const float vsum = oacc[ct][rr] + Red[w][rq * 4 + rr][o];
                Out[(((size_t)b * NF + f) * NT + t) * NDOUT + o] =
                    vsum + Bias[((size_t)f * NT + t) * NDOUT + o];
            }
        }
    }
}

extern "C" void kernel_launch(void* const* d_in, const int* in_sizes, int n_in,
                              void* d_out, int out_size, void* d_ws, size_t ws_size,
                              hipStream_t stream) {
    (void)in_sizes; (void)n_in; (void)ws_size; (void)out_size;
    const float* X    = (const float*)d_in[0];
    const float* Wq   = (const float*)d_in[1];
    const float* Wk   = (const float*)d_in[2];
    const float* Wkey = (const float*)d_in[3];
    const float* U    = (const float*)d_in[4];
    const float* AC   = (const float*)d_in[5];
    const float* Al   = (const float*)d_in[6];
    // d_in[7] = R is analytic (delta^2, delta), folded into score formula
    const float* Wo   = (const float*)d_in[8];
    const float* Bias = (const float*)d_in[9];

    float* q_ws = (float*)d_ws;                       // 2 MB
    float* k_ws = q_ws + (size_t)NBS * NT * 16 * NF;  // 2 MB

    qk_project_kernel<<<dim3(NT * NF / 4), dim3(256), 0, stream>>>(X, Wq, Wk, q_ws, k_ws);
    spatial_attn_kernel<<<dim3(NBS * NT), dim3(1024), 0, stream>>>(
        X, q_ws, k_ws, Wkey, U, AC, Al, Wo, Bias, (float*)d_out);
}

// Round 7
// 54.399 us; speedup vs baseline: 3.0660x; 3.0660x over previous
//
#include <hip/hip_runtime.h>
#include <hip/hip_bf16.h>

#define NBS 8
#define NT 32
#define NF 128
#define NDIN 64
#define NNH 8
#define NDOUT 64

typedef __bf16 bf16_t;
typedef __bf16 bf16x8 __attribute__((ext_vector_type(8)));
typedef float f32x4 __attribute__((ext_vector_type(4)));

// ---------------- kernel 1: q/k projection ----------------
// One wave per (t,f): q[b,he] = sum_d X[b,f,t,d] * Wq[t,f,d,he], all 8 b at once.
// Wq/Wk/X each read exactly once from HBM -> ~46MB -> memory-bound ~8us.
__global__ __launch_bounds__(256, 4)
void qk_project_kernel(const float* __restrict__ X,
                       const float* __restrict__ Wq,
                       const float* __restrict__ Wk,
                       float* __restrict__ q_ws,
                       float* __restrict__ k_ws)
{
    __shared__ float lx[4][8][64];
    const int w = threadIdx.x >> 6, lane = threadIdx.x & 63;
    const int gw = blockIdx.x * 4 + w;
    const int t = gw >> 7, f = gw & 127;

    {
        const int b = lane >> 3, d8 = (lane & 7) << 3;
        const float* src = &X[(((size_t)b * NF + f) * NT + t) * NDIN + d8];
        const float4 v0 = *(const float4*)src;
        const float4 v1 = *(const float4*)(src + 4);
        *(float4*)&lx[w][b][d8]     = v0;
        *(float4*)&lx[w][b][d8 + 4] = v1;
    }
    __syncthreads();

    const int dq = lane >> 4, he = lane & 15;
    const float* wq = Wq + ((size_t)t * NF + f) * (NDIN * 16);
    const float* wk = Wk + ((size_t)t * NF + f) * (NDIN * 16);
    float qa[8] = {0,0,0,0,0,0,0,0}, ka[8] = {0,0,0,0,0,0,0,0};
    for (int d0 = 0; d0 < NDIN; d0 += 4) {
        const int d = d0 + dq;
        const float wqv = wq[d * 16 + he];
        const float wkv = wk[d * 16 + he];
#pragma unroll
        for (int b = 0; b < 8; ++b) {
            const float x = lx[w][b][d];
            qa[b] = fmaf(x, wqv, qa[b]);
            ka[b] = fmaf(x, wkv, ka[b]);
        }
    }
#pragma unroll
    for (int b = 0; b < 8; ++b) {
        qa[b] += __shfl_xor(qa[b], 16); qa[b] += __shfl_xor(qa[b], 32);
        ka[b] += __shfl_xor(ka[b], 16); ka[b] += __shfl_xor(ka[b], 32);
    }
#pragma unroll
    for (int bb = 0; bb < 2; ++bb) {
        const int b = dq + bb * 4;
        q_ws[(((size_t)b * NT + t) * 16 + he) * NF + f] = qa[b];
        k_ws[(((size_t)b * NT + t) * 16 + he) * NF + f] = ka[b];
    }
}

// ---------------- kernel 2: attention + output GEMMs ----------------
// One block per (b,t), 512 threads = 8 waves. Wave w = row-tile rt (16 f-rows),
// loops over ALL 8 heads -> oacc complete per wave -> no cross-wave reduction,
// ONE barrier total. 512-thread workgroups escape the 64-VGPR cap observed at
// flat-wg=1024 (r4/r5: 64 VGPR + 300MB spill traffic; r1/r2 at 512thr: 88 VGPR,
// no spill). Math identical to the r4/r5 PASSING path: single-pass sc[4][8],
// P normalized (sc*rinv) BEFORE the MFMA (per-A-frag-row scalar — folding it
// after the MFMA was r6's wrong-row bug).
__global__ __launch_bounds__(512, 2)
void spatial_attn_kernel(const float* __restrict__ X,
                         const float* __restrict__ q_ws,
                         const float* __restrict__ k_ws,
                         const float* __restrict__ Wkey,
                         const float* __restrict__ U,
                         const float* __restrict__ AC,
                         const float* __restrict__ Alpha,
                         const float* __restrict__ Wo,
                         const float* __restrict__ Bias,
                         float* __restrict__ Out)
{
    const int blk  = blockIdx.x;
    const int b    = blk & 7;
    const int t    = blk >> 3;
    const int tid  = threadIdx.x;
    const int w    = tid >> 6;
    const int lane = tid & 63;
    const int cq   = lane & 15;
    const int rq   = lane >> 4;
    const int rt   = w;            // row tile 0..7
    const int frow = 16 * rt + cq;

    // LDS carve: 142336 B total (<= 160 KiB)
    __shared__ __align__(16) unsigned char smem[142336];
    bf16_t (*XT)[NF + 8]        = (bf16_t (*)[NF + 8])(smem);             // [64][136]   17408
    float4 (*kv)[136]           = (float4 (*)[136])(smem + 17408);        // [8][136]    17408  {k0,k1,u0,u1}(h,l)
    float4 (*qf)[128]           = (float4 (*)[128])(smem + 34816);        // [8][128]    16384  {q0,q1,kf0,kf1}(h,f)
    bf16_t (*WTall)[NDOUT][72]  = (bf16_t (*)[NDOUT][72])(smem + 51200);  // [8][64][72] 73728
    bf16_t (*Vscr)[16][68]      = (bf16_t (*)[16][68])(smem + 124928);    // [8][16][68] 17408

    // ---- stage XT (X^T bf16): 2048 float4 over 512 threads ----
#pragma unroll
    for (int r = 0; r < 4; ++r) {
        const int idx = tid + r * 512;
        const int f = idx >> 4, d4 = (idx & 15) << 2;
        const float4 v = *(const float4*)&X[(((size_t)b * NF + f) * NT + t) * NDIN + d4];
        XT[d4 + 0][f] = (bf16_t)v.x; XT[d4 + 1][f] = (bf16_t)v.y;
        XT[d4 + 2][f] = (bf16_t)v.z; XT[d4 + 3][f] = (bf16_t)v.w;
    }
    // ---- stage kv and qf: 1024 (h,l) pairs over 512 threads ----
#pragma unroll
    for (int r = 0; r < 2; ++r) {
        const int idx = tid + r * 512;
        const int hh = idx >> 7, l = idx & 127;
        const size_t qkb = ((size_t)b * NT + t) * 16;
        const float k0 = k_ws[(qkb + 2 * hh + 0) * NF + l];
        const float k1 = k_ws[(qkb + 2 * hh + 1) * NF + l];
        const float2 u01 = *(const float2*)&U[((size_t)t * NF + l) * 2];
        kv[hh][17 * (l >> 4) + (l & 15)] = make_float4(k0, k1, u01.x, u01.y);
        const float q0 = q_ws[(qkb + 2 * hh + 0) * NF + l];
        const float q1 = q_ws[(qkb + 2 * hh + 1) * NF + l];
        qf[hh][l] = make_float4(q0, q1, k0, k1);
    }
    // ---- stage WTall[h][o][d] = W[t][h*64+d][o] (bf16): 8192 float4 ----
#pragma unroll
    for (int rep = 0; rep < 16; ++rep) {
        const int flat = rep * 512 + tid;
        const int h = flat >> 10, f10 = flat & 1023;
        const int d = f10 >> 4, o4 = (f10 & 15) << 2;
        const float4 v = *(const float4*)&Wo[((size_t)t * 512 + h * 64 + d) * NDOUT + o4];
        WTall[h][o4 + 0][d] = (bf16_t)v.x; WTall[h][o4 + 1][d] = (bf16_t)v.y;
        WTall[h][o4 + 2][d] = (bf16_t)v.z; WTall[h][o4 + 3][d] = (bf16_t)v.w;
    }

    const float alpha_t = Alpha[t];
    const float wk00 = Wkey[t * 4 + 0], wk01 = Wkey[t * 4 + 1];
    const float wk10 = Wkey[t * 4 + 2], wk11 = Wkey[t * 4 + 3];

    __syncthreads();   // the ONLY barrier

    f32x4 oacc[4] = { {0.f,0.f,0.f,0.f}, {0.f,0.f,0.f,0.f}, {0.f,0.f,0.f,0.f}, {0.f,0.f,0.f,0.f} };

#pragma unroll 1
    for (int h = 0; h < NNH; ++h) {
        const float4 qq = qf[h][frow];            // {q0,q1,kf0,kf1} for this row
        const float q0 = qq.x, q1 = qq.y, kf0 = qq.z, kf1 = qq.w;
        const float v1 = 2.f * alpha_t * AC[t * NNH + h];
        const float c0 = (q0 - alpha_t) * wk00 + (q1 + v1) * wk10;
        const float c1 = (q0 - alpha_t) * wk01 + (q1 + v1) * wk11;

        // scores in A-frag layout: sc[kt][j] = S[frow][kt*32 + rq*8 + j]
        float sc[4][8];
        float rowmax = -3.0e38f;
#pragma unroll
        for (int kt = 0; kt < 4; ++kt) {
            const int s  = kt * 2 + (rq >> 1);
            const int i0 = (rq & 1) << 3;
            const float4* kvp = &kv[h][17 * s + i0];
            float del = (float)(kt * 32 + rq * 8 - frow);
#pragma unroll
            for (int j = 0; j < 8; ++j) {
                const float4 kj = kvp[j];
                const float sv = q0 * kj.x + q1 * kj.y + kf0 * kj.z + kf1 * kj.w
                               + (c0 * del + c1) * del;
                sc[kt][j] = sv;
                rowmax = fmaxf(rowmax, sv);
                del += 1.f;
            }
        }
        // row reduce across rq lanes (cq fixed): xor 16, 32
        rowmax = fmaxf(rowmax, __shfl_xor(rowmax, 16));
        rowmax = fmaxf(rowmax, __shfl_xor(rowmax, 32));
        float sum = 0.f;
#pragma unroll
        for (int kt = 0; kt < 4; ++kt)
#pragma unroll
            for (int j = 0; j < 8; ++j) {
                sc[kt][j] = __expf(sc[kt][j] - rowmax);
                sum += sc[kt][j];
            }
        sum += __shfl_xor(sum, 16);
        sum += __shfl_xor(sum, 32);
        const float rinv = 1.f / sum;

        // GEMM1: V[16x64] = P[16x128] @ X[128x64]; P normalized pre-MFMA
        f32x4 vacc[4] = { {0.f,0.f,0.f,0.f}, {0.f,0.f,0.f,0.f}, {0.f,0.f,0.f,0.f}, {0.f,0.f,0.f,0.f} };
#pragma unroll
        for (int kt = 0; kt < 4; ++kt) {
            bf16x8 pf;
#pragma unroll
            for (int j = 0; j < 8; ++j) pf[j] = (bf16_t)(sc[kt][j] * rinv);
#pragma unroll
            for (int ct = 0; ct < 4; ++ct) {
                const bf16x8 bb = *(const bf16x8*)&XT[ct * 16 + cq][kt * 32 + rq * 8];
                vacc[ct] = __builtin_amdgcn_mfma_f32_16x16x32_bf16(pf, bb, vacc[ct], 0, 0, 0);
            }
        }
        // V C-frags -> private wave scratch (intra-wave dep only, no barrier)
#pragma unroll
        for (int ct = 0; ct < 4; ++ct)
#pragma unroll
            for (int rr = 0; rr < 4; ++rr)
                Vscr[w][rq * 4 + rr][ct * 16 + cq] = (bf16_t)vacc[ct][rr];

        // GEMM2: oacc += V[16x64] @ W_h[64x64]
#pragma unroll
        for (int kt = 0; kt < 2; ++kt) {
            const bf16x8 a = *(const bf16x8*)&Vscr[w][cq][kt * 32 + rq * 8];
#pragma unroll
            for (int ct = 0; ct < 4; ++ct) {
                const bf16x8 bw = *(const bf16x8*)&WTall[h][ct * 16 + cq][kt * 32 + rq * 8];
                oacc[ct] = __builtin_amdgcn_mfma_f32_16x16x32_bf16(a, bw, oacc[ct], 0, 0, 0);
            }
        }
    }

    // ---- epilogue: Out = oacc + bias (oacc complete: all 8 heads done here) ----
#pragma unroll
    for (int ct = 0; ct < 4; ++ct) {
#pragma unroll
        for (int rr = 0; rr < 4; ++rr) {
            const int f = 16 * rt + rq * 4 + rr;
            const int o = ct * 16 + cq;
            Out[(((size_t)b * NF + f) * NT + t) * NDOUT + o] =
                oacc[ct][rr] + Bias[((size_t)f * NT + t) * NDOUT + o];
        }
    }
}

extern "C" void kernel_launch(void* const* d_in, const int* in_sizes, int n_in,
                              void* d_out, int out_size, void* d_ws, size_t ws_size,
                              hipStream_t stream) {
    (void)in_sizes; (void)n_in; (void)ws_size; (void)out_size;
    const float* X    = (const float*)d_in[0];
    const float* Wq   = (const float*)d_in[1];
    const float* Wk   = (const float*)d_in[2];
    const float* Wkey = (const float*)d_in[3];
    const float* U    = (const float*)d_in[4];
    const float* AC   = (const float*)d_in[5];
    const float* Al   = (const float*)d_in[6];
    // d_in[7] = R is analytic (delta^2, delta), folded into score formula
    const float* Wo   = (const float*)d_in[8];
    const float* Bias = (const float*)d_in[9];

    float* q_ws = (float*)d_ws;                       // 2 MB
    float* k_ws = q_ws + (size_t)NBS * NT * 16 * NF;  // 2 MB

    qk_project_kernel<<<dim3(NT * NF / 4), dim3(256), 0, stream>>>(X, Wq, Wk, q_ws, k_ws);
    spatial_attn_kernel<<<dim3(NBS * NT), dim3(512), 0, stream>>>(
        X, q_ws, k_ws, Wkey, U, AC, Al, Wo, Bias, (float*)d_out);
}